// Round 1
// baseline (172.930 us; speedup 1.0000x reference)
//
#include <hip/hip_runtime.h>

// AttentionFlow: B=8, N=50000, D=32, N_SRC=12500, DEG=8, R=500
// E = 800000 edges, segments of exactly DEG=8 consecutive edges (idx_vi == e>>3).
//
// One 64-lane wave handles one segment (8 edges). Lane layout:
//   k = lane>>3  : edge within segment (0..7)
//   q = lane&7   : float4 dim-quad (D=32 = 8 quads)
// All gathered rows (32 floats = 128B, 128B-aligned) are read as 8 coalesced
// float4 loads. Dot-reduce over q via shfl_xor(1,2,4); segment softmax over k
// via shfl_xor(8,16,32). No LDS, no __syncthreads.

#define DDIM 32

__global__ __launch_bounds__(256) void attn_flow_kernel(
    const float* __restrict__ node_attention,   // B*N
    const float* __restrict__ hidden_con,       // B*N*D
    const float* __restrict__ hidden_uncon,     // N*D
    const float* __restrict__ edges_y,          // E
    const float* __restrict__ rel_emb,          // R*D
    const float* __restrict__ ws,               // 4*D
    const float* __restrict__ bvec,             // D
    const float* __restrict__ out_w,            // D
    const float* __restrict__ out_b,            // D
    const int*   __restrict__ edges,            // E*6 (idx, vi, vj, rel, idx_vi, key)
    float* __restrict__ trans_attention,        // E
    float* __restrict__ new_node_attention,     // B*N
    int n_groups, int N_nodes)
{
    const int gid  = (int)((blockIdx.x * (unsigned)blockDim.x + threadIdx.x) >> 6);
    if (gid >= n_groups) return;
    const int lane = threadIdx.x & 63;
    const int k = lane >> 3;   // edge within segment
    const int q = lane & 7;    // dim quad

    const long e = (long)gid * 8 + k;
    const int* __restrict__ erow = edges + e * 6;

    // idx, vi are uniform across the segment: read from edge 0 of the group.
    const int idx = edges[(long)gid * 48 + 0];
    const int vi  = edges[(long)gid * 48 + 1];
    const int vj  = erow[2];
    const int rel = erow[3];

    const long base_con = ((long)idx * N_nodes) * DDIM;

    const float4 hvi = ((const float4*)(hidden_con + base_con + (long)vi * DDIM))[q];
    const float4 hvj = ((const float4*)(hidden_con + base_con + (long)vj * DDIM))[q];
    const float4 huj = ((const float4*)(hidden_uncon + (long)vj * DDIM))[q];
    const float4 re  = ((const float4*)(rel_emb + rel * DDIM))[q];

    const float4 w0 = ((const float4*)(ws          ))[q];
    const float4 w1 = ((const float4*)(ws +   DDIM))[q];
    const float4 w2 = ((const float4*)(ws + 2*DDIM))[q];
    const float4 w3 = ((const float4*)(ws + 3*DDIM))[q];
    const float4 bb = ((const float4*)(bvec ))[q];
    const float4 ow = ((const float4*)(out_w))[q];
    const float4 ob = ((const float4*)(out_b))[q];

    // h = hcvi*(hcvj*(w0 + re*w1) + huvj*(w2 + re*w3)) + b ; relu ; *out_w + out_b
    float part;
    {
        float h0 = hvi.x * (hvj.x * fmaf(re.x, w1.x, w0.x) + huj.x * fmaf(re.x, w3.x, w2.x)) + bb.x;
        float h1 = hvi.y * (hvj.y * fmaf(re.y, w1.y, w0.y) + huj.y * fmaf(re.y, w3.y, w2.y)) + bb.y;
        float h2 = hvi.z * (hvj.z * fmaf(re.z, w1.z, w0.z) + huj.z * fmaf(re.z, w3.z, w2.z)) + bb.z;
        float h3 = hvi.w * (hvj.w * fmaf(re.w, w1.w, w0.w) + huj.w * fmaf(re.w, w3.w, w2.w)) + bb.w;
        h0 = fmaf(fmaxf(h0, 0.f), ow.x, ob.x);
        h1 = fmaf(fmaxf(h1, 0.f), ow.y, ob.y);
        h2 = fmaf(fmaxf(h2, 0.f), ow.z, ob.z);
        h3 = fmaf(fmaxf(h3, 0.f), ow.w, ob.w);
        part = (h0 + h1) + (h2 + h3);
    }

    // reduce over the 8 dim-quad lanes -> logit for edge k (replicated in its 8 lanes)
    part += __shfl_xor(part, 1, 64);
    part += __shfl_xor(part, 2, 64);
    part += __shfl_xor(part, 4, 64);
    const float logit = part;

    // segment softmax across the 8 edges (lanes strided by 8)
    float m = logit;
    m = fmaxf(m, __shfl_xor(m, 8, 64));
    m = fmaxf(m, __shfl_xor(m, 16, 64));
    m = fmaxf(m, __shfl_xor(m, 32, 64));
    const float ex = expf(logit - m);
    float s = ex;
    s += __shfl_xor(s, 8, 64);
    s += __shfl_xor(s, 16, 64);
    s += __shfl_xor(s, 32, 64);
    const float transition = ex / s;

    if (q == 0) {
        const float na = node_attention[(long)idx * N_nodes + vi];  // segment-uniform
        const float ta = na * transition * edges_y[e];
        trans_attention[e] = ta;
        atomicAdd(new_node_attention + (long)idx * N_nodes + vj, ta);
    }
}

extern "C" void kernel_launch(void* const* d_in, const int* in_sizes, int n_in,
                              void* d_out, int out_size, void* d_ws, size_t ws_size,
                              hipStream_t stream) {
    const float* node_attention = (const float*)d_in[0];
    const float* hidden_con    = (const float*)d_in[1];
    const float* hidden_uncon  = (const float*)d_in[2];
    const float* edges_y       = (const float*)d_in[3];
    const float* rel_emb       = (const float*)d_in[4];
    const float* ws            = (const float*)d_in[5];
    const float* bvec          = (const float*)d_in[6];
    const float* out_w         = (const float*)d_in[7];
    const float* out_b         = (const float*)d_in[8];
    const int*   edges         = (const int*)d_in[9];

    const int E        = in_sizes[9] / 6;     // 800000
    const int BN       = in_sizes[0];         // B*N = 400000
    const int N_nodes  = in_sizes[2] / DDIM;  // 50000
    const int n_groups = E / 8;               // 100000

    float* trans_attention     = (float*)d_out;
    float* new_node_attention  = (float*)d_out + E;

    // d_out is poisoned 0xAA before every timed launch -> zero the scatter target.
    hipMemsetAsync(new_node_attention, 0, (size_t)BN * sizeof(float), stream);

    const int waves_per_block = 4;                       // 256 threads
    const int blocks = (n_groups + waves_per_block - 1) / waves_per_block;
    attn_flow_kernel<<<blocks, 256, 0, stream>>>(
        node_attention, hidden_con, hidden_uncon, edges_y, rel_emb,
        ws, bvec, out_w, out_b, edges,
        trans_attention, new_node_attention, n_groups, N_nodes);
}